// Round 4
// baseline (853.796 us; speedup 1.0000x reference)
//
#include <hip/hip_runtime.h>

#define HID 64
#define HEADS 4
#define DMODEL 256
#define NPW 8  // nodes per wave in post kernel

// ---------------------------------------------------------------------------
// Detect whether edge_index arrived as int64 (JAX x64 on) or int32 (x64 off).
// For int64 little-endian, odd int32 words are high halves == 0 (values < 50000).
__global__ void detect_i64_kernel(const int* __restrict__ ei, int* __restrict__ flag) {
    if (threadIdx.x == 0 && blockIdx.x == 0) {
        int all0 = 1;
        for (int j = 0; j < 32; ++j) {
            if (ei[2 * j + 1] != 0) { all0 = 0; break; }
        }
        flag[0] = all0;  // 1 -> int64 layout
    }
}

__device__ __forceinline__ int load_edge(const void* ei, int is64, size_t idx) {
    if (is64) return (int)((const long long*)ei)[idx];
    return ((const int*)ei)[idx];
}

// ---------------------------------------------------------------------------
// CSR build: histogram of in-degree per dst
__global__ void hist_kernel(const void* __restrict__ ei, const int* __restrict__ flag,
                            int* __restrict__ deg, int E) {
    int e = blockIdx.x * blockDim.x + threadIdx.x;
    if (e >= E) return;
    int is64 = flag[0];
    int d = load_edge(ei, is64, (size_t)E + e);
    atomicAdd(&deg[d], 1);
}

// Single-block 3-phase exclusive scan over N (~50000):
// phase 1: each thread serially sums `per` contiguous elements
// phase 2: Hillis-Steele over the 1024 partial sums (10 steps, ~20 barriers)
// phase 3: each thread serially emits running prefixes for its chunk
__global__ __launch_bounds__(1024) void scan_kernel(
        const int* __restrict__ deg, int* __restrict__ offs,
        int* __restrict__ cursor, int n) {
    __shared__ int sums[1024];
    const int t = threadIdx.x;
    const int per = (n + 1023) / 1024;
    const int s0 = t * per;
    int sum = 0;
    for (int i = 0; i < per; ++i) {
        const int idx = s0 + i;
        if (idx < n) sum += deg[idx];
    }
    sums[t] = sum;
    __syncthreads();
    for (int offv = 1; offv < 1024; offv <<= 1) {
        const int add = (t >= offv) ? sums[t - offv] : 0;
        __syncthreads();
        sums[t] += add;
        __syncthreads();
    }
    int run = (t > 0) ? sums[t - 1] : 0;  // exclusive base of this chunk
    for (int i = 0; i < per; ++i) {
        const int idx = s0 + i;
        if (idx < n) {
            offs[idx] = run;
            cursor[idx] = run;
            run += deg[idx];
        }
    }
    if (t == 1023) offs[n] = sums[1023];
}

// Scatter src ids into per-dst buckets
__global__ void fill_kernel(const void* __restrict__ ei, const int* __restrict__ flag,
                            int* __restrict__ cursor, int* __restrict__ ssrc, int E) {
    int e = blockIdx.x * blockDim.x + threadIdx.x;
    if (e >= E) return;
    int is64 = flag[0];
    int s = load_edge(ei, is64, (size_t)e);
    int d = load_edge(ei, is64, (size_t)E + e);
    int pos = atomicAdd(&cursor[d], 1);
    ssrc[pos] = s;
}

// ---------------------------------------------------------------------------
// q/k/v/skip = x @ W.T + b for four [256,64] weight matrices.
// blockIdx.y selects the matrix; 4 waves x 64 lanes each own one output column o,
// with the W row held in 64 VGPRs; x rows are wave-uniform (scalarizable) loads.
__global__ __launch_bounds__(256) void qkvs_gemm_kernel(
        const float* __restrict__ x,
        const float* __restrict__ W0, const float* __restrict__ b0,
        const float* __restrict__ W1, const float* __restrict__ b1,
        const float* __restrict__ W2, const float* __restrict__ b2,
        const float* __restrict__ W3, const float* __restrict__ b3,
        float* __restrict__ o0, float* __restrict__ o1,
        float* __restrict__ o2, float* __restrict__ o3,
        int n) {
    const float* W; const float* bb; float* out;
    switch (blockIdx.y) {
        case 0:  W = W0; bb = b0; out = o0; break;
        case 1:  W = W1; bb = b1; out = o1; break;
        case 2:  W = W2; bb = b2; out = o2; break;
        default: W = W3; bb = b3; out = o3; break;
    }
    const int wave = threadIdx.x >> 6, lane = threadIdx.x & 63;
    const int o = wave * 64 + lane;  // 0..255 output column

    float wr[64];
#pragma unroll
    for (int j = 0; j < 16; ++j) {
        const float4 t = *(const float4*)(W + o * 64 + j * 4);
        wr[4 * j + 0] = t.x; wr[4 * j + 1] = t.y;
        wr[4 * j + 2] = t.z; wr[4 * j + 3] = t.w;
    }
    const float bias = bb[o];
    const int n0 = blockIdx.x * 64;
    for (int ni = 0; ni < 64; ++ni) {
        const int nn = n0 + ni;
        const int nc = nn < n ? nn : n - 1;
        const float* __restrict__ xr = x + (size_t)nc * 64;
        float a0 = 0.f, a1 = 0.f;
#pragma unroll
        for (int j = 0; j < 32; ++j) {
            a0 = fmaf(wr[j], xr[j], a0);
            a1 = fmaf(wr[32 + j], xr[32 + j], a1);
        }
        if (nn < n) out[(size_t)nn * DMODEL + o] = a0 + a1 + bias;
    }
}

// ---------------------------------------------------------------------------
// Per-dst-node attention: one wave per node, online softmax over CSR edges.
// lane layout: head g = lane>>4, 4 channels per lane (c0 = lane*4) -> each
// k/v row load is ONE fully-coalesced 1KB wave transaction.
// 1-deep software pipeline: next edge's k/v rows in flight during the
// current online-softmax update (ssrc read 2 ahead).
// NOTE: ob may alias qb — each wave reads only its own node's q row, before
// the single terminal write to that row; no other wave touches it.
__global__ __launch_bounds__(256) void attn_kernel(
        const float* __restrict__ qb, const float* __restrict__ kb,
        const float* __restrict__ vb,
        const int* __restrict__ offs, const int* __restrict__ ssrc,
        float* __restrict__ ob, int n) {
    const int wave = threadIdx.x >> 6, lane = threadIdx.x & 63;
    const int node = blockIdx.x * 4 + wave;
    if (node >= n) return;
    const int c0 = lane * 4;

    const float4 q4 = *(const float4*)(qb + (size_t)node * DMODEL + c0);
    const int start = offs[node];
    const int end = offs[node + 1];

    float m = -INFINITY, ssum = 0.f;
    float4 acc = {0.f, 0.f, 0.f, 0.f};

    float4 kc = {0.f, 0.f, 0.f, 0.f}, vc = kc;
    int sn_nxt = 0;
    if (start < end) {
        const int sn0 = ssrc[start];
        kc = *(const float4*)(kb + (size_t)sn0 * DMODEL + c0);
        vc = *(const float4*)(vb + (size_t)sn0 * DMODEL + c0);
        if (start + 1 < end) sn_nxt = ssrc[start + 1];
    }

    for (int i = start; i < end; ++i) {
        float4 kn, vn;
        kn.x = kn.y = kn.z = kn.w = 0.f;
        vn = kn;
        if (i + 1 < end) {  // wave-uniform
            kn = *(const float4*)(kb + (size_t)sn_nxt * DMODEL + c0);
            vn = *(const float4*)(vb + (size_t)sn_nxt * DMODEL + c0);
        }
        const int sn2 = (i + 2 < end) ? ssrc[i + 2] : 0;

        float p = q4.x * kc.x + q4.y * kc.y + q4.z * kc.z + q4.w * kc.w;
        // reduce within 16-lane head group
        p += __shfl_xor(p, 1);
        p += __shfl_xor(p, 2);
        p += __shfl_xor(p, 4);
        p += __shfl_xor(p, 8);
        const float a = p * 0.125f;  // / sqrt(64)

        const float mnew = fmaxf(m, a);
        const float r = __expf(m - mnew);    // exp(-inf)=0 on first edge
        const float pe = __expf(a - mnew);
        ssum = ssum * r + pe;
        acc.x = acc.x * r + vc.x * pe;
        acc.y = acc.y * r + vc.y * pe;
        acc.z = acc.z * r + vc.z * pe;
        acc.w = acc.w * r + vc.w * pe;
        m = mnew;

        kc = kn; vc = vn; sn_nxt = sn2;
    }
    const float inv = (end > start) ? 1.f / ssum : 0.f;
    float4 o;
    o.x = acc.x * inv; o.y = acc.y * inv; o.z = acc.z * inv; o.w = acc.w * inv;
    *(float4*)(ob + (size_t)node * DMODEL + c0) = o;
}

// ---------------------------------------------------------------------------
// beta-gate + LayerNorm + proj(256->64) + residual + relu.
// One wave processes NPW=8 nodes: phase A computes beta-gate + LN per node,
// keeping all 8 LN rows in registers (ln4[8], lane l holds channels 4l..4l+3).
// Phase B does proj with weight chunks read ONCE per 8 nodes: lane l owns
// output row h=l; W[l][4j..4j+3] stored as float4 chunk wp4[l*64 + (j^l)]
// (XOR swizzle: lane->chunk is a bijection per j -> same bank histogram as
// linear -> conflict-free ds_read_b128; staging writes likewise bijective).
// LDS = 64KB exactly. LDS-pipe cost ~8 b128/node (vs 256 b32/node before).
__global__ __launch_bounds__(256) void post_kernel(
        const float* __restrict__ attn, const float* __restrict__ skip,
        const float* __restrict__ x,
        const float* __restrict__ Wbeta,
        const float* __restrict__ ln_g, const float* __restrict__ ln_b,
        const float* __restrict__ Wproj, const float* __restrict__ bproj,
        float* __restrict__ out, int n) {
    __shared__ float4 wp4[64 * 64];

    // stage: global float4 f = (h = f>>6, j = f&63); within a wave h is
    // uniform and j = lane -> coalesced global read, bijective LDS write.
    for (int f = threadIdx.x; f < 64 * 64; f += 256) {
        const int h = f >> 6, j = f & 63;
        wp4[h * 64 + (j ^ h)] = ((const float4*)Wproj)[f];
    }
    __syncthreads();

    const int wave = threadIdx.x >> 6, lane = threadIdx.x & 63;
    const int c0 = lane * 4;
    const float4 wb0 = *(const float4*)(Wbeta + c0);
    const float4 wb1 = *(const float4*)(Wbeta + 256 + c0);
    const float4 wb2 = *(const float4*)(Wbeta + 512 + c0);
    const float4 g4 = *(const float4*)(ln_g + c0);
    const float4 bb4 = *(const float4*)(ln_b + c0);
    const float bp = bproj[lane];

    const int base = (blockIdx.x * 4 + wave) * NPW;
    float4 ln4[NPW];

    // ---- phase A: beta-gate + LayerNorm per node (results in registers)
#pragma unroll
    for (int ni = 0; ni < NPW; ++ni) {
        const int nn = base + ni;
        const int nc = (nn < n) ? nn : n - 1;  // clamp; invalid lanes discarded later
        const float4 o4 = *(const float4*)(attn + (size_t)nc * DMODEL + c0);
        const float4 s4 = *(const float4*)(skip + (size_t)nc * DMODEL + c0);

        // beta = sigmoid(dot(out, wb0+wb2) + dot(skip, wb1-wb2))
        float bpart = o4.x * (wb0.x + wb2.x) + s4.x * (wb1.x - wb2.x)
                    + o4.y * (wb0.y + wb2.y) + s4.y * (wb1.y - wb2.y)
                    + o4.z * (wb0.z + wb2.z) + s4.z * (wb1.z - wb2.z)
                    + o4.w * (wb0.w + wb2.w) + s4.w * (wb1.w - wb2.w);
#pragma unroll
        for (int mk = 1; mk <= 32; mk <<= 1) bpart += __shfl_xor(bpart, mk);
        const float beta = 1.f / (1.f + __expf(-bpart));

        float4 u;
        u.x = beta * s4.x + (1.f - beta) * o4.x;
        u.y = beta * s4.y + (1.f - beta) * o4.y;
        u.z = beta * s4.z + (1.f - beta) * o4.z;
        u.w = beta * s4.w + (1.f - beta) * o4.w;

        float ps = u.x + u.y + u.z + u.w;
        float pq = u.x * u.x + u.y * u.y + u.z * u.z + u.w * u.w;
#pragma unroll
        for (int mk = 1; mk <= 32; mk <<= 1) {
            ps += __shfl_xor(ps, mk);
            pq += __shfl_xor(pq, mk);
        }
        const float mu = ps * (1.f / 256.f);
        const float var = pq * (1.f / 256.f) - mu * mu;
        const float rstd = rsqrtf(var + 1e-5f);

        ln4[ni].x = (u.x - mu) * rstd * g4.x + bb4.x;
        ln4[ni].y = (u.y - mu) * rstd * g4.y + bb4.y;
        ln4[ni].z = (u.z - mu) * rstd * g4.z + bb4.z;
        ln4[ni].w = (u.w - mu) * rstd * g4.w + bb4.w;
    }

    // ---- phase B: proj for all 8 nodes; weight chunk read once per j
    float acc[NPW];
#pragma unroll
    for (int ni = 0; ni < NPW; ++ni) acc[ni] = bp;

    for (int j = 0; j < 64; ++j) {
        const float4 w = wp4[lane * 64 + (j ^ lane)];  // W[lane][4j..4j+3]
#pragma unroll
        for (int ni = 0; ni < NPW; ++ni) {
            const float l0 = __shfl(ln4[ni].x, j);
            const float l1 = __shfl(ln4[ni].y, j);
            const float l2 = __shfl(ln4[ni].z, j);
            const float l3 = __shfl(ln4[ni].w, j);
            acc[ni] = fmaf(w.x, l0, acc[ni]);
            acc[ni] = fmaf(w.y, l1, acc[ni]);
            acc[ni] = fmaf(w.z, l2, acc[ni]);
            acc[ni] = fmaf(w.w, l3, acc[ni]);
        }
    }

#pragma unroll
    for (int ni = 0; ni < NPW; ++ni) {
        const int nn = base + ni;
        if (nn < n) {
            const float res = acc[ni] + x[(size_t)nn * HID + lane];
            out[(size_t)nn * HID + lane] = fmaxf(res, 0.f);
        }
    }
}

// ---------------------------------------------------------------------------
extern "C" void kernel_launch(void* const* d_in, const int* in_sizes, int n_in,
                              void* d_out, int out_size, void* d_ws, size_t ws_size,
                              hipStream_t stream) {
    const float* x     = (const float*)d_in[0];
    const void*  ei    = d_in[1];
    const float* Wq    = (const float*)d_in[2];
    const float* bq    = (const float*)d_in[3];
    const float* Wk    = (const float*)d_in[4];
    const float* bk    = (const float*)d_in[5];
    const float* Wv    = (const float*)d_in[6];
    const float* bv    = (const float*)d_in[7];
    const float* Ws    = (const float*)d_in[8];
    const float* bs    = (const float*)d_in[9];
    const float* Wbeta = (const float*)d_in[10];
    const float* lng   = (const float*)d_in[11];
    const float* lnb   = (const float*)d_in[12];
    const float* Wp    = (const float*)d_in[13];
    const float* bp    = (const float*)d_in[14];
    float* out = (float*)d_out;

    const int N = in_sizes[0] / HID;
    const int E = in_sizes[1] / 2;

    char* w = (char*)d_ws;
    size_t off = 0;
    auto take = [&](size_t bytes) -> char* {
        char* p = w + off;
        off += (bytes + 255) & ~(size_t)255;
        return p;
    };
    float* qb     = (float*)take((size_t)N * DMODEL * 4);
    float* kb     = (float*)take((size_t)N * DMODEL * 4);
    float* vb     = (float*)take((size_t)N * DMODEL * 4);
    float* sb     = (float*)take((size_t)N * DMODEL * 4);
    int*   deg    = (int*)take((size_t)N * 4);
    int*   offs   = (int*)take((size_t)(N + 1) * 4);
    int*   cursor = (int*)take((size_t)N * 4);
    int*   ssrc   = (int*)take((size_t)E * 4);
    int*   flag   = (int*)take(256);
    float* ob     = qb;  // safe alias: see attn_kernel note

    detect_i64_kernel<<<1, 64, 0, stream>>>((const int*)ei, flag);
    hipMemsetAsync(deg, 0, (size_t)N * 4, stream);
    hist_kernel<<<(E + 255) / 256, 256, 0, stream>>>(ei, flag, deg, E);
    scan_kernel<<<1, 1024, 0, stream>>>(deg, offs, cursor, N);
    fill_kernel<<<(E + 255) / 256, 256, 0, stream>>>(ei, flag, cursor, ssrc, E);
    qkvs_gemm_kernel<<<dim3((N + 63) / 64, 4), 256, 0, stream>>>(
        x, Wq, bq, Wk, bk, Wv, bv, Ws, bs, qb, kb, vb, sb, N);
    attn_kernel<<<(N + 3) / 4, 256, 0, stream>>>(qb, kb, vb, offs, ssrc, ob, N);
    post_kernel<<<(N + 4 * NPW - 1) / (4 * NPW), 256, 0, stream>>>(
        ob, sb, x, Wbeta, lng, lnb, Wp, bp, out, N);
}

// Round 7
// 609.850 us; speedup vs baseline: 1.4000x; 1.4000x over previous
//
#include <hip/hip_runtime.h>

#define HID 64
#define HEADS 4
#define DMODEL 256
#define NPW 8  // nodes per wave in post kernel

// bf16 <-> f32 helpers (RNE pack)
__device__ __forceinline__ float bf2f(unsigned short u) {
    union { unsigned int i; float f; } c; c.i = ((unsigned int)u) << 16; return c.f;
}
__device__ __forceinline__ unsigned short f2bf(float f) {
    union { float f; unsigned int i; } c; c.f = f;
    const unsigned int x = c.i;
    return (unsigned short)((x + 0x7FFFu + ((x >> 16) & 1u)) >> 16);
}

// ---------------------------------------------------------------------------
// Detect whether edge_index arrived as int64 (JAX x64 on) or int32 (x64 off).
__global__ void detect_i64_kernel(const int* __restrict__ ei, int* __restrict__ flag) {
    if (threadIdx.x == 0 && blockIdx.x == 0) {
        int all0 = 1;
        for (int j = 0; j < 32; ++j) {
            if (ei[2 * j + 1] != 0) { all0 = 0; break; }
        }
        flag[0] = all0;  // 1 -> int64 layout
    }
}

__device__ __forceinline__ int load_edge(const void* ei, int is64, size_t idx) {
    if (is64) return (int)((const long long*)ei)[idx];
    return ((const int*)ei)[idx];
}

// ---------------------------------------------------------------------------
// CSR build: histogram of in-degree per dst
__global__ void hist_kernel(const void* __restrict__ ei, const int* __restrict__ flag,
                            int* __restrict__ deg, int E) {
    int e = blockIdx.x * blockDim.x + threadIdx.x;
    if (e >= E) return;
    int is64 = flag[0];
    int d = load_edge(ei, is64, (size_t)E + e);
    atomicAdd(&deg[d], 1);
}

// Coalesced 3-phase scan: A) per-1024-block inclusive scan + block totals,
// B) scan of block totals (<=1024 blocks), C) add base + emit exclusive.
__global__ __launch_bounds__(1024) void scanA_kernel(
        const int* __restrict__ deg, int* __restrict__ loc,
        int* __restrict__ bsum, int n) {
    __shared__ int lds[1024];
    const int t = threadIdx.x, idx = blockIdx.x * 1024 + t;
    const int v = (idx < n) ? deg[idx] : 0;
    int val = v;
    lds[t] = val;
    __syncthreads();
    for (int o = 1; o < 1024; o <<= 1) {
        const int add = (t >= o) ? lds[t - o] : 0;
        __syncthreads();
        val += add;
        lds[t] = val;
        __syncthreads();
    }
    if (idx < n) loc[idx] = val;  // inclusive within block
    if (t == 1023) bsum[blockIdx.x] = val;
}

__global__ __launch_bounds__(1024) void scanB_kernel(int* __restrict__ bsum, int nb) {
    __shared__ int lds[1024];
    const int t = threadIdx.x;
    int val = (t < nb) ? bsum[t] : 0;
    lds[t] = val;
    __syncthreads();
    for (int o = 1; o < 1024; o <<= 1) {
        const int add = (t >= o) ? lds[t - o] : 0;
        __syncthreads();
        val += add;
        lds[t] = val;
        __syncthreads();
    }
    if (t < nb) bsum[t] = val;  // inclusive block bases
}

__global__ void scanC_kernel(const int* __restrict__ deg, const int* __restrict__ loc,
                             const int* __restrict__ bsum,
                             int* __restrict__ offs, int* __restrict__ cursor,
                             int n, int nb) {
    const int idx = blockIdx.x * blockDim.x + threadIdx.x;
    if (idx > n) return;
    if (idx == n) { offs[n] = bsum[nb - 1]; return; }
    const int b = idx >> 10;
    const int ex = ((b > 0) ? bsum[b - 1] : 0) + loc[idx] - deg[idx];
    offs[idx] = ex;
    cursor[idx] = ex;
}

// Scatter src ids into per-dst buckets
__global__ void fill_kernel(const void* __restrict__ ei, const int* __restrict__ flag,
                            int* __restrict__ cursor, int* __restrict__ ssrc, int E) {
    int e = blockIdx.x * blockDim.x + threadIdx.x;
    if (e >= E) return;
    int is64 = flag[0];
    int s = load_edge(ei, is64, (size_t)e);
    int d = load_edge(ei, is64, (size_t)E + e);
    int pos = atomicAdd(&cursor[d], 1);
    ssrc[pos] = s;
}

// ---------------------------------------------------------------------------
// q/k/v/skip = x @ W.T + b. blockIdx.y: 0=q(f32) 1=k(bf16->kv.lo) 2=v(bf16->kv.hi)
// 3=skip(f32). 4 waves x 64 lanes own one output column each (W row in 64
// VGPRs); x rows are wave-uniform float4 loads (broadcast across lanes).
// k/v passes write disjoint ushorts of the interleaved kv buffer.
__global__ __launch_bounds__(256) void qkvs_gemm_kernel(
        const float* __restrict__ x,
        const float* __restrict__ Wq, const float* __restrict__ bq,
        const float* __restrict__ Wk, const float* __restrict__ bk,
        const float* __restrict__ Wv, const float* __restrict__ bv,
        const float* __restrict__ Ws, const float* __restrict__ bs,
        float* __restrict__ qO, unsigned int* __restrict__ kvO,
        float* __restrict__ sO,
        int n) {
    const float* W; const float* bb;
    switch (blockIdx.y) {
        case 0:  W = Wq; bb = bq; break;
        case 1:  W = Wk; bb = bk; break;
        case 2:  W = Wv; bb = bv; break;
        default: W = Ws; bb = bs; break;
    }
    const int wave = threadIdx.x >> 6, lane = threadIdx.x & 63;
    const int o = wave * 64 + lane;  // 0..255 output column

    float wr[64];
#pragma unroll
    for (int j = 0; j < 16; ++j) {
        const float4 t = *(const float4*)(W + o * 64 + j * 4);
        wr[4 * j + 0] = t.x; wr[4 * j + 1] = t.y;
        wr[4 * j + 2] = t.z; wr[4 * j + 3] = t.w;
    }
    const float bias = bb[o];
    const int n0 = blockIdx.x * 64;
    for (int ni = 0; ni < 64; ++ni) {
        const int nn = n0 + ni;
        const int nc = nn < n ? nn : n - 1;
        const float4* __restrict__ xr4 = (const float4*)(x + (size_t)nc * 64);
        float a0 = 0.f, a1 = 0.f, a2 = 0.f, a3 = 0.f;
#pragma unroll
        for (int j = 0; j < 16; ++j) {
            const float4 xv = xr4[j];
            a0 = fmaf(wr[4 * j + 0], xv.x, a0);
            a1 = fmaf(wr[4 * j + 1], xv.y, a1);
            a2 = fmaf(wr[4 * j + 2], xv.z, a2);
            a3 = fmaf(wr[4 * j + 3], xv.w, a3);
        }
        const float val = (a0 + a1) + (a2 + a3) + bias;
        if (nn < n) {
            const size_t oi = (size_t)nn * DMODEL + o;
            if (blockIdx.y == 0)      qO[oi] = val;
            else if (blockIdx.y == 1) ((unsigned short*)kvO)[oi * 2 + 0] = f2bf(val);
            else if (blockIdx.y == 2) ((unsigned short*)kvO)[oi * 2 + 1] = f2bf(val);
            else                      sO[oi] = val;
        }
    }
}

// ---------------------------------------------------------------------------
// Per-dst-node attention: one wave per node, online softmax over CSR edges.
// kv is channel-interleaved bf16 (k lo16, v hi16): a node's kv row is 1KB
// contiguous; each lane reads ONE uint4 (16B, channels c0..c0+3) -> the whole
// edge gather is a single fully-coalesced 1KB dwordx4 wave transaction
// (vs 2x512B separate k/v rows). lane layout: head = lane>>4, c0 = lane*4.
// 1-deep software pipeline: next edge's kv row in flight during the update.
// NOTE: ob aliases qb (fp32) — each wave reads only its own node's q row,
// before the single terminal write to that row; no other wave touches it.
__global__ __launch_bounds__(256) void attn_kernel(
        const float* __restrict__ qb, const unsigned int* __restrict__ kvb,
        const int* __restrict__ offs, const int* __restrict__ ssrc,
        float* __restrict__ ob, int n) {
    const int wave = threadIdx.x >> 6, lane = threadIdx.x & 63;
    const int node = blockIdx.x * 4 + wave;
    if (node >= n) return;
    const int c0 = lane * 4;

    const float4 q4 = *(const float4*)(qb + (size_t)node * DMODEL + c0);
    const int start = offs[node];
    const int end = offs[node + 1];

    float m = -INFINITY, ssum = 0.f;
    float4 acc = {0.f, 0.f, 0.f, 0.f};

    uint4 kvc = {0u, 0u, 0u, 0u};
    int sn_nxt = 0;
    if (start < end) {
        const int sn0 = ssrc[start];
        kvc = *(const uint4*)(kvb + (size_t)sn0 * DMODEL + c0);
        if (start + 1 < end) sn_nxt = ssrc[start + 1];
    }

    for (int i = start; i < end; ++i) {
        uint4 kvn = {0u, 0u, 0u, 0u};
        if (i + 1 < end) {  // wave-uniform
            kvn = *(const uint4*)(kvb + (size_t)sn_nxt * DMODEL + c0);
        }
        const int sn2 = (i + 2 < end) ? ssrc[i + 2] : 0;

        float p = q4.x * bf2f((unsigned short)(kvc.x & 0xFFFFu))
                + q4.y * bf2f((unsigned short)(kvc.y & 0xFFFFu))
                + q4.z * bf2f((unsigned short)(kvc.z & 0xFFFFu))
                + q4.w * bf2f((unsigned short)(kvc.w & 0xFFFFu));
        // reduce within 16-lane head group
        p += __shfl_xor(p, 1);
        p += __shfl_xor(p, 2);
        p += __shfl_xor(p, 4);
        p += __shfl_xor(p, 8);
        const float a = p * 0.125f;  // / sqrt(64)

        const float mnew = fmaxf(m, a);
        const float r = __expf(m - mnew);    // exp(-inf)=0 on first edge
        const float pe = __expf(a - mnew);
        ssum = ssum * r + pe;
        acc.x = acc.x * r + bf2f((unsigned short)(kvc.x >> 16)) * pe;
        acc.y = acc.y * r + bf2f((unsigned short)(kvc.y >> 16)) * pe;
        acc.z = acc.z * r + bf2f((unsigned short)(kvc.z >> 16)) * pe;
        acc.w = acc.w * r + bf2f((unsigned short)(kvc.w >> 16)) * pe;
        m = mnew;

        kvc = kvn; sn_nxt = sn2;
    }
    const float inv = (end > start) ? 1.f / ssum : 0.f;
    float4 o;
    o.x = acc.x * inv; o.y = acc.y * inv; o.z = acc.z * inv; o.w = acc.w * inv;
    *(float4*)(ob + (size_t)node * DMODEL + c0) = o;
}

// ---------------------------------------------------------------------------
// beta-gate + LayerNorm + proj(256->64) + residual + relu.
// One wave processes NPW=8 nodes: phase A computes beta-gate + LN per node,
// keeping all 8 LN rows in registers (ln4[8], lane l holds channels 4l..4l+3).
// Phase B: proj with weight chunks read ONCE per 8 nodes; W[l][4j..4j+3] at
// float4 chunk wp4[l*64 + (j^l)] (XOR swizzle: lane->chunk bijection per j ->
// conflict-free ds_read_b128 both sides). LDS = 64KB.
__global__ __launch_bounds__(256) void post_kernel(
        const float* __restrict__ attn, const float* __restrict__ skip,
        const float* __restrict__ x,
        const float* __restrict__ Wbeta,
        const float* __restrict__ ln_g, const float* __restrict__ ln_b,
        const float* __restrict__ Wproj, const float* __restrict__ bproj,
        float* __restrict__ out, int n) {
    __shared__ float4 wp4[64 * 64];

    for (int f = threadIdx.x; f < 64 * 64; f += 256) {
        const int h = f >> 6, j = f & 63;
        wp4[h * 64 + (j ^ h)] = ((const float4*)Wproj)[f];
    }
    __syncthreads();

    const int wave = threadIdx.x >> 6, lane = threadIdx.x & 63;
    const int c0 = lane * 4;
    const float4 wb0 = *(const float4*)(Wbeta + c0);
    const float4 wb1 = *(const float4*)(Wbeta + 256 + c0);
    const float4 wb2 = *(const float4*)(Wbeta + 512 + c0);
    const float4 g4 = *(const float4*)(ln_g + c0);
    const float4 bb4 = *(const float4*)(ln_b + c0);
    const float bp = bproj[lane];

    const int base = (blockIdx.x * 4 + wave) * NPW;
    float4 ln4[NPW];

    // ---- phase A: beta-gate + LayerNorm per node (results in registers)
#pragma unroll
    for (int ni = 0; ni < NPW; ++ni) {
        const int nn = base + ni;
        const int nc = (nn < n) ? nn : n - 1;  // clamp; tail discarded at store
        const float4 o4 = *(const float4*)(attn + (size_t)nc * DMODEL + c0);
        const float4 s4 = *(const float4*)(skip + (size_t)nc * DMODEL + c0);

        float bpart = o4.x * (wb0.x + wb2.x) + s4.x * (wb1.x - wb2.x)
                    + o4.y * (wb0.y + wb2.y) + s4.y * (wb1.y - wb2.y)
                    + o4.z * (wb0.z + wb2.z) + s4.z * (wb1.z - wb2.z)
                    + o4.w * (wb0.w + wb2.w) + s4.w * (wb1.w - wb2.w);
#pragma unroll
        for (int mk = 1; mk <= 32; mk <<= 1) bpart += __shfl_xor(bpart, mk);
        const float beta = 1.f / (1.f + __expf(-bpart));

        float4 u;
        u.x = beta * s4.x + (1.f - beta) * o4.x;
        u.y = beta * s4.y + (1.f - beta) * o4.y;
        u.z = beta * s4.z + (1.f - beta) * o4.z;
        u.w = beta * s4.w + (1.f - beta) * o4.w;

        float ps = u.x + u.y + u.z + u.w;
        float pq = u.x * u.x + u.y * u.y + u.z * u.z + u.w * u.w;
#pragma unroll
        for (int mk = 1; mk <= 32; mk <<= 1) {
            ps += __shfl_xor(ps, mk);
            pq += __shfl_xor(pq, mk);
        }
        const float mu = ps * (1.f / 256.f);
        const float var = pq * (1.f / 256.f) - mu * mu;
        const float rstd = rsqrtf(var + 1e-5f);

        ln4[ni].x = (u.x - mu) * rstd * g4.x + bb4.x;
        ln4[ni].y = (u.y - mu) * rstd * g4.y + bb4.y;
        ln4[ni].z = (u.z - mu) * rstd * g4.z + bb4.z;
        ln4[ni].w = (u.w - mu) * rstd * g4.w + bb4.w;
    }

    // ---- phase B: proj for all 8 nodes; weight chunk read once per j
    float acc[NPW];
#pragma unroll
    for (int ni = 0; ni < NPW; ++ni) acc[ni] = bp;

    for (int j = 0; j < 64; ++j) {
        const float4 w = wp4[lane * 64 + (j ^ lane)];  // W[lane][4j..4j+3]
#pragma unroll
        for (int ni = 0; ni < NPW; ++ni) {
            const float l0 = __shfl(ln4[ni].x, j);
            const float l1 = __shfl(ln4[ni].y, j);
            const float l2 = __shfl(ln4[ni].z, j);
            const float l3 = __shfl(ln4[ni].w, j);
            acc[ni] = fmaf(w.x, l0, acc[ni]);
            acc[ni] = fmaf(w.y, l1, acc[ni]);
            acc[ni] = fmaf(w.z, l2, acc[ni]);
            acc[ni] = fmaf(w.w, l3, acc[ni]);
        }
    }

#pragma unroll
    for (int ni = 0; ni < NPW; ++ni) {
        const int nn = base + ni;
        if (nn < n) {
            const float res = acc[ni] + x[(size_t)nn * HID + lane];
            out[(size_t)nn * HID + lane] = fmaxf(res, 0.f);
        }
    }
}

// ---------------------------------------------------------------------------
extern "C" void kernel_launch(void* const* d_in, const int* in_sizes, int n_in,
                              void* d_out, int out_size, void* d_ws, size_t ws_size,
                              hipStream_t stream) {
    const float* x     = (const float*)d_in[0];
    const void*  ei    = d_in[1];
    const float* Wq    = (const float*)d_in[2];
    const float* bq    = (const float*)d_in[3];
    const float* Wk    = (const float*)d_in[4];
    const float* bk    = (const float*)d_in[5];
    const float* Wv    = (const float*)d_in[6];
    const float* bv    = (const float*)d_in[7];
    const float* Ws    = (const float*)d_in[8];
    const float* bs    = (const float*)d_in[9];
    const float* Wbeta = (const float*)d_in[10];
    const float* lng   = (const float*)d_in[11];
    const float* lnb   = (const float*)d_in[12];
    const float* Wp    = (const float*)d_in[13];
    const float* bp    = (const float*)d_in[14];
    float* out = (float*)d_out;

    const int N = in_sizes[0] / HID;
    const int E = in_sizes[1] / 2;
    const int NB = (N + 1023) / 1024;

    char* w = (char*)d_ws;
    size_t off = 0;
    auto take = [&](size_t bytes) -> char* {
        char* p = w + off;
        off += (bytes + 255) & ~(size_t)255;
        return p;
    };
    float*        qb     = (float*)take((size_t)N * DMODEL * 4);
    unsigned int* kvb    = (unsigned int*)take((size_t)N * DMODEL * 4);
    float*        sb     = (float*)take((size_t)N * DMODEL * 4);
    int*          deg    = (int*)take((size_t)N * 4);
    int*          loc    = (int*)take((size_t)N * 4);
    int*          bsum   = (int*)take((size_t)NB * 4);
    int*          offs   = (int*)take((size_t)(N + 1) * 4);
    int*          cursor = (int*)take((size_t)N * 4);
    int*          ssrc   = (int*)take((size_t)E * 4);
    int*          flag   = (int*)take(256);
    float*        ob     = qb;  // safe alias: see attn_kernel note

    detect_i64_kernel<<<1, 64, 0, stream>>>((const int*)ei, flag);
    hipMemsetAsync(deg, 0, (size_t)N * 4, stream);
    hist_kernel<<<(E + 255) / 256, 256, 0, stream>>>(ei, flag, deg, E);
    scanA_kernel<<<NB, 1024, 0, stream>>>(deg, loc, bsum, N);
    scanB_kernel<<<1, 1024, 0, stream>>>(bsum, NB);
    scanC_kernel<<<(N + 256) / 256, 256, 0, stream>>>(deg, loc, bsum, offs, cursor, N, NB);
    fill_kernel<<<(E + 255) / 256, 256, 0, stream>>>(ei, flag, cursor, ssrc, E);
    qkvs_gemm_kernel<<<dim3((N + 63) / 64, 4), 256, 0, stream>>>(
        x, Wq, bq, Wk, bk, Wv, bv, Ws, bs, qb, kvb, sb, N);
    attn_kernel<<<(N + 3) / 4, 256, 0, stream>>>(qb, kvb, offs, ssrc, ob, N);
    post_kernel<<<(N + 4 * NPW - 1) / (4 * NPW), 256, 0, stream>>>(
        ob, sb, x, Wbeta, lng, lnb, Wp, bp, out, N);
}

// Round 10
// 526.725 us; speedup vs baseline: 1.6210x; 1.1578x over previous
//
#include <hip/hip_runtime.h>

#define HID 64
#define HEADS 4
#define DMODEL 256
#define NPW 8  // nodes per wave in post kernel

// bf16 <-> f32 helpers (RNE pack)
__device__ __forceinline__ float bf2f(unsigned short u) {
    union { unsigned int i; float f; } c; c.i = ((unsigned int)u) << 16; return c.f;
}
__device__ __forceinline__ unsigned short f2bf(float f) {
    union { float f; unsigned int i; } c; c.f = f;
    const unsigned int x = c.i;
    return (unsigned short)((x + 0x7FFFu + ((x >> 16) & 1u)) >> 16);
}
// wave-uniform lane broadcast via v_readlane (VALU, no LDS pipe)
__device__ __forceinline__ float rdl(float v, int l) {
    return __int_as_float(__builtin_amdgcn_readlane(__float_as_int(v), l));
}

// ---------------------------------------------------------------------------
// Detect whether edge_index arrived as int64 (JAX x64 on) or int32 (x64 off).
__global__ void detect_i64_kernel(const int* __restrict__ ei, int* __restrict__ flag) {
    if (threadIdx.x == 0 && blockIdx.x == 0) {
        int all0 = 1;
        for (int j = 0; j < 32; ++j) {
            if (ei[2 * j + 1] != 0) { all0 = 0; break; }
        }
        flag[0] = all0;  // 1 -> int64 layout
    }
}

__device__ __forceinline__ int load_edge(const void* ei, int is64, size_t idx) {
    if (is64) return (int)((const long long*)ei)[idx];
    return ((const int*)ei)[idx];
}

// ---------------------------------------------------------------------------
// CSR build: histogram of in-degree per dst
__global__ void hist_kernel(const void* __restrict__ ei, const int* __restrict__ flag,
                            int* __restrict__ deg, int E) {
    int e = blockIdx.x * blockDim.x + threadIdx.x;
    if (e >= E) return;
    int is64 = flag[0];
    int d = load_edge(ei, is64, (size_t)E + e);
    atomicAdd(&deg[d], 1);
}

// Coalesced 3-phase scan: A) per-1024-block inclusive scan + block totals,
// B) scan of block totals (<=1024 blocks), C) add base + emit exclusive.
__global__ __launch_bounds__(1024) void scanA_kernel(
        const int* __restrict__ deg, int* __restrict__ loc,
        int* __restrict__ bsum, int n) {
    __shared__ int lds[1024];
    const int t = threadIdx.x, idx = blockIdx.x * 1024 + t;
    const int v = (idx < n) ? deg[idx] : 0;
    int val = v;
    lds[t] = val;
    __syncthreads();
    for (int o = 1; o < 1024; o <<= 1) {
        const int add = (t >= o) ? lds[t - o] : 0;
        __syncthreads();
        val += add;
        lds[t] = val;
        __syncthreads();
    }
    if (idx < n) loc[idx] = val;  // inclusive within block
    if (t == 1023) bsum[blockIdx.x] = val;
}

__global__ __launch_bounds__(1024) void scanB_kernel(int* __restrict__ bsum, int nb) {
    __shared__ int lds[1024];
    const int t = threadIdx.x;
    int val = (t < nb) ? bsum[t] : 0;
    lds[t] = val;
    __syncthreads();
    for (int o = 1; o < 1024; o <<= 1) {
        const int add = (t >= o) ? lds[t - o] : 0;
        __syncthreads();
        val += add;
        lds[t] = val;
        __syncthreads();
    }
    if (t < nb) bsum[t] = val;  // inclusive block bases
}

__global__ void scanC_kernel(const int* __restrict__ deg, const int* __restrict__ loc,
                             const int* __restrict__ bsum,
                             int* __restrict__ offs, int* __restrict__ cursor,
                             int n, int nb) {
    const int idx = blockIdx.x * blockDim.x + threadIdx.x;
    if (idx > n) return;
    if (idx == n) { offs[n] = bsum[nb - 1]; return; }
    const int b = idx >> 10;
    const int ex = ((b > 0) ? bsum[b - 1] : 0) + loc[idx] - deg[idx];
    offs[idx] = ex;
    cursor[idx] = ex;
}

// Scatter src ids into per-dst buckets
__global__ void fill_kernel(const void* __restrict__ ei, const int* __restrict__ flag,
                            int* __restrict__ cursor, int* __restrict__ ssrc, int E) {
    int e = blockIdx.x * blockDim.x + threadIdx.x;
    if (e >= E) return;
    int is64 = flag[0];
    int s = load_edge(ei, is64, (size_t)e);
    int d = load_edge(ei, is64, (size_t)E + e);
    int pos = atomicAdd(&cursor[d], 1);
    ssrc[pos] = s;
}

// ---------------------------------------------------------------------------
// q/k/v/skip = x @ W.T + b. blockIdx.y: 0=q(f32) 1=k(bf16->kv.lo) 2=v(bf16->kv.hi)
// 3=skip(f32). 4 waves x 64 lanes own one output column each (W row in 64
// VGPRs); x rows are wave-uniform float4 loads (broadcast across lanes).
// k/v passes write disjoint ushorts of the interleaved kv buffer.
__global__ __launch_bounds__(256) void qkvs_gemm_kernel(
        const float* __restrict__ x,
        const float* __restrict__ Wq, const float* __restrict__ bq,
        const float* __restrict__ Wk, const float* __restrict__ bk,
        const float* __restrict__ Wv, const float* __restrict__ bv,
        const float* __restrict__ Ws, const float* __restrict__ bs,
        float* __restrict__ qO, unsigned int* __restrict__ kvO,
        float* __restrict__ sO,
        int n) {
    const float* W; const float* bb;
    switch (blockIdx.y) {
        case 0:  W = Wq; bb = bq; break;
        case 1:  W = Wk; bb = bk; break;
        case 2:  W = Wv; bb = bv; break;
        default: W = Ws; bb = bs; break;
    }
    const int wave = threadIdx.x >> 6, lane = threadIdx.x & 63;
    const int o = wave * 64 + lane;  // 0..255 output column

    float wr[64];
#pragma unroll
    for (int j = 0; j < 16; ++j) {
        const float4 t = *(const float4*)(W + o * 64 + j * 4);
        wr[4 * j + 0] = t.x; wr[4 * j + 1] = t.y;
        wr[4 * j + 2] = t.z; wr[4 * j + 3] = t.w;
    }
    const float bias = bb[o];
    const int n0 = blockIdx.x * 64;
    for (int ni = 0; ni < 64; ++ni) {
        const int nn = n0 + ni;
        const int nc = nn < n ? nn : n - 1;
        const float4* __restrict__ xr4 = (const float4*)(x + (size_t)nc * 64);
        float a0 = 0.f, a1 = 0.f, a2 = 0.f, a3 = 0.f;
#pragma unroll
        for (int j = 0; j < 16; ++j) {
            const float4 xv = xr4[j];
            a0 = fmaf(wr[4 * j + 0], xv.x, a0);
            a1 = fmaf(wr[4 * j + 1], xv.y, a1);
            a2 = fmaf(wr[4 * j + 2], xv.z, a2);
            a3 = fmaf(wr[4 * j + 3], xv.w, a3);
        }
        const float val = (a0 + a1) + (a2 + a3) + bias;
        if (nn < n) {
            const size_t oi = (size_t)nn * DMODEL + o;
            if (blockIdx.y == 0)      qO[oi] = val;
            else if (blockIdx.y == 1) ((unsigned short*)kvO)[oi * 2 + 0] = f2bf(val);
            else if (blockIdx.y == 2) ((unsigned short*)kvO)[oi * 2 + 1] = f2bf(val);
            else                      sO[oi] = val;
        }
    }
}

// ---------------------------------------------------------------------------
// Per-dst-node attention: one wave per node, online softmax over CSR edges.
// kv is channel-interleaved bf16 (k lo16, v hi16): a node's kv row is 1KB
// contiguous; each lane reads ONE uint4 (16B, channels c0..c0+3) -> the whole
// edge gather is a single fully-coalesced 1KB dwordx4 wave transaction.
// 1-deep software pipeline: next edge's kv row in flight during the update.
// NOTE: ob aliases qb (fp32) — each wave reads only its own node's q row,
// before the single terminal write to that row; no other wave touches it.
__global__ __launch_bounds__(256) void attn_kernel(
        const float* __restrict__ qb, const unsigned int* __restrict__ kvb,
        const int* __restrict__ offs, const int* __restrict__ ssrc,
        float* __restrict__ ob, int n) {
    const int wave = threadIdx.x >> 6, lane = threadIdx.x & 63;
    const int node = blockIdx.x * 4 + wave;
    if (node >= n) return;
    const int c0 = lane * 4;

    const float4 q4 = *(const float4*)(qb + (size_t)node * DMODEL + c0);
    const int start = offs[node];
    const int end = offs[node + 1];

    float m = -INFINITY, ssum = 0.f;
    float4 acc = {0.f, 0.f, 0.f, 0.f};

    uint4 kvc = {0u, 0u, 0u, 0u};
    int sn_nxt = 0;
    if (start < end) {
        const int sn0 = ssrc[start];
        kvc = *(const uint4*)(kvb + (size_t)sn0 * DMODEL + c0);
        if (start + 1 < end) sn_nxt = ssrc[start + 1];
    }

    for (int i = start; i < end; ++i) {
        uint4 kvn = {0u, 0u, 0u, 0u};
        if (i + 1 < end) {  // wave-uniform
            kvn = *(const uint4*)(kvb + (size_t)sn_nxt * DMODEL + c0);
        }
        const int sn2 = (i + 2 < end) ? ssrc[i + 2] : 0;

        float p = q4.x * bf2f((unsigned short)(kvc.x & 0xFFFFu))
                + q4.y * bf2f((unsigned short)(kvc.y & 0xFFFFu))
                + q4.z * bf2f((unsigned short)(kvc.z & 0xFFFFu))
                + q4.w * bf2f((unsigned short)(kvc.w & 0xFFFFu));
        // reduce within 16-lane head group
        p += __shfl_xor(p, 1);
        p += __shfl_xor(p, 2);
        p += __shfl_xor(p, 4);
        p += __shfl_xor(p, 8);
        const float a = p * 0.125f;  // / sqrt(64)

        const float mnew = fmaxf(m, a);
        const float r = __expf(m - mnew);    // exp(-inf)=0 on first edge
        const float pe = __expf(a - mnew);
        ssum = ssum * r + pe;
        acc.x = acc.x * r + bf2f((unsigned short)(kvc.x >> 16)) * pe;
        acc.y = acc.y * r + bf2f((unsigned short)(kvc.y >> 16)) * pe;
        acc.z = acc.z * r + bf2f((unsigned short)(kvc.z >> 16)) * pe;
        acc.w = acc.w * r + bf2f((unsigned short)(kvc.w >> 16)) * pe;
        m = mnew;

        kvc = kvn; sn_nxt = sn2;
    }
    const float inv = (end > start) ? 1.f / ssum : 0.f;
    float4 o;
    o.x = acc.x * inv; o.y = acc.y * inv; o.z = acc.z * inv; o.w = acc.w * inv;
    *(float4*)(ob + (size_t)node * DMODEL + c0) = o;
}

// ---------------------------------------------------------------------------
// beta-gate + LayerNorm + proj(256->64) + residual + relu.
// One wave processes NPW=8 nodes. Phase A: beta-gate + LN per node, all 8 LN
// rows kept in registers (ln4[8]; lane l holds channels 4l..4l+3).
// Phase B: proj WITHOUT LDS — weights read directly from global (W[lane][4j..]
// one float4/lane/j, 64KB/wave from the L2-resident 64KB Wproj; reused across
// all 8 nodes), and the ln broadcast uses v_readlane (VALU) instead of
// __shfl/ds_bpermute. Round-7 counters showed the old version was LDS-pipe/
// latency-bound: 64KB LDS -> 2 blocks/CU (19% occupancy), 2048 bpermute +
// 64 ds_read per wave through one LDS pipe, VALUBusy 12%. Zero LDS now.
__global__ __launch_bounds__(256) void post_kernel(
        const float* __restrict__ attn, const float* __restrict__ skip,
        const float* __restrict__ x,
        const float* __restrict__ Wbeta,
        const float* __restrict__ ln_g, const float* __restrict__ ln_b,
        const float* __restrict__ Wproj, const float* __restrict__ bproj,
        float* __restrict__ out, int n) {
    const int wave = threadIdx.x >> 6, lane = threadIdx.x & 63;
    const int c0 = lane * 4;
    const float4 wb0 = *(const float4*)(Wbeta + c0);
    const float4 wb1 = *(const float4*)(Wbeta + 256 + c0);
    const float4 wb2 = *(const float4*)(Wbeta + 512 + c0);
    const float4 g4 = *(const float4*)(ln_g + c0);
    const float4 bb4 = *(const float4*)(ln_b + c0);
    const float bp = bproj[lane];

    const int base = (blockIdx.x * 4 + wave) * NPW;
    float4 ln4[NPW];

    // ---- phase A: beta-gate + LayerNorm per node (results in registers)
#pragma unroll
    for (int ni = 0; ni < NPW; ++ni) {
        const int nn = base + ni;
        const int nc = (nn < n) ? nn : n - 1;  // clamp; tail discarded at store
        const float4 o4 = *(const float4*)(attn + (size_t)nc * DMODEL + c0);
        const float4 s4 = *(const float4*)(skip + (size_t)nc * DMODEL + c0);

        float bpart = o4.x * (wb0.x + wb2.x) + s4.x * (wb1.x - wb2.x)
                    + o4.y * (wb0.y + wb2.y) + s4.y * (wb1.y - wb2.y)
                    + o4.z * (wb0.z + wb2.z) + s4.z * (wb1.z - wb2.z)
                    + o4.w * (wb0.w + wb2.w) + s4.w * (wb1.w - wb2.w);
#pragma unroll
        for (int mk = 1; mk <= 32; mk <<= 1) bpart += __shfl_xor(bpart, mk);
        const float beta = 1.f / (1.f + __expf(-bpart));

        float4 u;
        u.x = beta * s4.x + (1.f - beta) * o4.x;
        u.y = beta * s4.y + (1.f - beta) * o4.y;
        u.z = beta * s4.z + (1.f - beta) * o4.z;
        u.w = beta * s4.w + (1.f - beta) * o4.w;

        float ps = u.x + u.y + u.z + u.w;
        float pq = u.x * u.x + u.y * u.y + u.z * u.z + u.w * u.w;
#pragma unroll
        for (int mk = 1; mk <= 32; mk <<= 1) {
            ps += __shfl_xor(ps, mk);
            pq += __shfl_xor(pq, mk);
        }
        const float mu = ps * (1.f / 256.f);
        const float var = pq * (1.f / 256.f) - mu * mu;
        const float rstd = rsqrtf(var + 1e-5f);

        ln4[ni].x = (u.x - mu) * rstd * g4.x + bb4.x;
        ln4[ni].y = (u.y - mu) * rstd * g4.y + bb4.y;
        ln4[ni].z = (u.z - mu) * rstd * g4.z + bb4.z;
        ln4[ni].w = (u.w - mu) * rstd * g4.w + bb4.w;
    }

    // ---- phase B: proj for all 8 nodes; weight float4 read once per j
    // (global, L2-resident), ln broadcast via v_readlane (uniform unrolled j)
    float acc[NPW];
#pragma unroll
    for (int ni = 0; ni < NPW; ++ni) acc[ni] = bp;

    const float4* __restrict__ Wp4 = (const float4*)Wproj;  // [64 rows][64 chunks]
#pragma unroll 4
    for (int j = 0; j < 64; ++j) {
        const float4 w = Wp4[lane * 64 + j];  // W[lane][4j..4j+3]
#pragma unroll
        for (int ni = 0; ni < NPW; ++ni) {
            acc[ni] = fmaf(w.x, rdl(ln4[ni].x, j), acc[ni]);
            acc[ni] = fmaf(w.y, rdl(ln4[ni].y, j), acc[ni]);
            acc[ni] = fmaf(w.z, rdl(ln4[ni].z, j), acc[ni]);
            acc[ni] = fmaf(w.w, rdl(ln4[ni].w, j), acc[ni]);
        }
    }

#pragma unroll
    for (int ni = 0; ni < NPW; ++ni) {
        const int nn = base + ni;
        if (nn < n) {
            const float res = acc[ni] + x[(size_t)nn * HID + lane];
            out[(size_t)nn * HID + lane] = fmaxf(res, 0.f);
        }
    }
}

// ---------------------------------------------------------------------------
extern "C" void kernel_launch(void* const* d_in, const int* in_sizes, int n_in,
                              void* d_out, int out_size, void* d_ws, size_t ws_size,
                              hipStream_t stream) {
    const float* x     = (const float*)d_in[0];
    const void*  ei    = d_in[1];
    const float* Wq    = (const float*)d_in[2];
    const float* bq    = (const float*)d_in[3];
    const float* Wk    = (const float*)d_in[4];
    const float* bk    = (const float*)d_in[5];
    const float* Wv    = (const float*)d_in[6];
    const float* bv    = (const float*)d_in[7];
    const float* Ws    = (const float*)d_in[8];
    const float* bs    = (const float*)d_in[9];
    const float* Wbeta = (const float*)d_in[10];
    const float* lng   = (const float*)d_in[11];
    const float* lnb   = (const float*)d_in[12];
    const float* Wp    = (const float*)d_in[13];
    const float* bp    = (const float*)d_in[14];
    float* out = (float*)d_out;

    const int N = in_sizes[0] / HID;
    const int E = in_sizes[1] / 2;
    const int NB = (N + 1023) / 1024;

    char* w = (char*)d_ws;
    size_t off = 0;
    auto take = [&](size_t bytes) -> char* {
        char* p = w + off;
        off += (bytes + 255) & ~(size_t)255;
        return p;
    };
    float*        qb     = (float*)take((size_t)N * DMODEL * 4);
    unsigned int* kvb    = (unsigned int*)take((size_t)N * DMODEL * 4);
    float*        sb     = (float*)take((size_t)N * DMODEL * 4);
    int*          deg    = (int*)take((size_t)N * 4);
    int*          loc    = (int*)take((size_t)N * 4);
    int*          bsum   = (int*)take((size_t)NB * 4);
    int*          offs   = (int*)take((size_t)(N + 1) * 4);
    int*          cursor = (int*)take((size_t)N * 4);
    int*          ssrc   = (int*)take((size_t)E * 4);
    int*          flag   = (int*)take(256);
    float*        ob     = qb;  // safe alias: see attn_kernel note

    detect_i64_kernel<<<1, 64, 0, stream>>>((const int*)ei, flag);
    hipMemsetAsync(deg, 0, (size_t)N * 4, stream);
    hist_kernel<<<(E + 255) / 256, 256, 0, stream>>>(ei, flag, deg, E);
    scanA_kernel<<<NB, 1024, 0, stream>>>(deg, loc, bsum, N);
    scanB_kernel<<<1, 1024, 0, stream>>>(bsum, NB);
    scanC_kernel<<<(N + 256) / 256, 256, 0, stream>>>(deg, loc, bsum, offs, cursor, N, NB);
    fill_kernel<<<(E + 255) / 256, 256, 0, stream>>>(ei, flag, cursor, ssrc, E);
    qkvs_gemm_kernel<<<dim3((N + 63) / 64, 4), 256, 0, stream>>>(
        x, Wq, bq, Wk, bk, Wv, bv, Ws, bs, qb, kvb, sb, N);
    attn_kernel<<<(N + 3) / 4, 256, 0, stream>>>(qb, kvb, offs, ssrc, ob, N);
    post_kernel<<<(N + 4 * NPW - 1) / (4 * NPW), 256, 0, stream>>>(
        ob, sb, x, Wbeta, lng, lnb, Wp, bp, out, N);
}

// Round 11
// 520.552 us; speedup vs baseline: 1.6402x; 1.0119x over previous
//
#include <hip/hip_runtime.h>

#define HID 64
#define HEADS 4
#define DMODEL 256
#define NPW 8  // nodes per wave in post kernel

// bf16 <-> f32 helpers (RNE pack)
__device__ __forceinline__ float bf2f(unsigned short u) {
    union { unsigned int i; float f; } c; c.i = ((unsigned int)u) << 16; return c.f;
}
__device__ __forceinline__ unsigned short f2bf(float f) {
    union { float f; unsigned int i; } c; c.f = f;
    const unsigned int x = c.i;
    return (unsigned short)((x + 0x7FFFu + ((x >> 16) & 1u)) >> 16);
}
// wave-uniform lane broadcast via v_readlane (VALU, no LDS pipe)
__device__ __forceinline__ float rdl(float v, int l) {
    return __int_as_float(__builtin_amdgcn_readlane(__float_as_int(v), l));
}

// ---------------------------------------------------------------------------
// Detect whether edge_index arrived as int64 (JAX x64 on) or int32 (x64 off).
__global__ void detect_i64_kernel(const int* __restrict__ ei, int* __restrict__ flag) {
    if (threadIdx.x == 0 && blockIdx.x == 0) {
        int all0 = 1;
        for (int j = 0; j < 32; ++j) {
            if (ei[2 * j + 1] != 0) { all0 = 0; break; }
        }
        flag[0] = all0;  // 1 -> int64 layout
    }
}

__device__ __forceinline__ int load_edge(const void* ei, int is64, size_t idx) {
    if (is64) return (int)((const long long*)ei)[idx];
    return ((const int*)ei)[idx];
}

// ---------------------------------------------------------------------------
// CSR build: histogram of in-degree per dst
__global__ void hist_kernel(const void* __restrict__ ei, const int* __restrict__ flag,
                            int* __restrict__ deg, int E) {
    int e = blockIdx.x * blockDim.x + threadIdx.x;
    if (e >= E) return;
    int is64 = flag[0];
    int d = load_edge(ei, is64, (size_t)E + e);
    atomicAdd(&deg[d], 1);
}

// Coalesced 3-phase scan: A) per-1024-block inclusive scan + block totals,
// B) scan of block totals (<=1024 blocks), C) add base + emit exclusive.
__global__ __launch_bounds__(1024) void scanA_kernel(
        const int* __restrict__ deg, int* __restrict__ loc,
        int* __restrict__ bsum, int n) {
    __shared__ int lds[1024];
    const int t = threadIdx.x, idx = blockIdx.x * 1024 + t;
    const int v = (idx < n) ? deg[idx] : 0;
    int val = v;
    lds[t] = val;
    __syncthreads();
    for (int o = 1; o < 1024; o <<= 1) {
        const int add = (t >= o) ? lds[t - o] : 0;
        __syncthreads();
        val += add;
        lds[t] = val;
        __syncthreads();
    }
    if (idx < n) loc[idx] = val;  // inclusive within block
    if (t == 1023) bsum[blockIdx.x] = val;
}

__global__ __launch_bounds__(1024) void scanB_kernel(int* __restrict__ bsum, int nb) {
    __shared__ int lds[1024];
    const int t = threadIdx.x;
    int val = (t < nb) ? bsum[t] : 0;
    lds[t] = val;
    __syncthreads();
    for (int o = 1; o < 1024; o <<= 1) {
        const int add = (t >= o) ? lds[t - o] : 0;
        __syncthreads();
        val += add;
        lds[t] = val;
        __syncthreads();
    }
    if (t < nb) bsum[t] = val;  // inclusive block bases
}

__global__ void scanC_kernel(const int* __restrict__ deg, const int* __restrict__ loc,
                             const int* __restrict__ bsum,
                             int* __restrict__ offs, int* __restrict__ cursor,
                             int n, int nb) {
    const int idx = blockIdx.x * blockDim.x + threadIdx.x;
    if (idx > n) return;
    if (idx == n) { offs[n] = bsum[nb - 1]; return; }
    const int b = idx >> 10;
    const int ex = ((b > 0) ? bsum[b - 1] : 0) + loc[idx] - deg[idx];
    offs[idx] = ex;
    cursor[idx] = ex;
}

// Scatter src ids into per-dst buckets
__global__ void fill_kernel(const void* __restrict__ ei, const int* __restrict__ flag,
                            int* __restrict__ cursor, int* __restrict__ ssrc, int E) {
    int e = blockIdx.x * blockDim.x + threadIdx.x;
    if (e >= E) return;
    int is64 = flag[0];
    int s = load_edge(ei, is64, (size_t)e);
    int d = load_edge(ei, is64, (size_t)E + e);
    int pos = atomicAdd(&cursor[d], 1);
    ssrc[pos] = s;
}

// ---------------------------------------------------------------------------
// q/k/v/skip = x @ W.T + b. blockIdx.y: 0=q(f32) 1=k(bf16->kv.lo) 2=v(bf16->kv.hi)
// 3=skip(f32). 4 waves x 64 lanes own one output column each, W row held in 64
// VGPRs. Round-10 counters showed VGPR_Count=40: the default-occupancy register
// budget evicted wr[64] (VALU 2.3x the 42us FMA floor -> one reload/mov per FMA).
// Fix: __launch_bounds__(256,4) caps at 128 VGPR so wr stays resident, and the
// K loop is chunked (4 x 16) with 1-chunk-ahead x prefetch so only 8 x-float4
// are live at once (64 wr + 32 x + misc ~= 111 regs). FLOP order identical.
__global__ __launch_bounds__(256, 4) void qkvs_gemm_kernel(
        const float* __restrict__ x,
        const float* __restrict__ Wq, const float* __restrict__ bq,
        const float* __restrict__ Wk, const float* __restrict__ bk,
        const float* __restrict__ Wv, const float* __restrict__ bv,
        const float* __restrict__ Ws, const float* __restrict__ bs,
        float* __restrict__ qO, unsigned int* __restrict__ kvO,
        float* __restrict__ sO,
        int n) {
    const float* W; const float* bb;
    switch (blockIdx.y) {
        case 0:  W = Wq; bb = bq; break;
        case 1:  W = Wk; bb = bk; break;
        case 2:  W = Wv; bb = bv; break;
        default: W = Ws; bb = bs; break;
    }
    const int wave = threadIdx.x >> 6, lane = threadIdx.x & 63;
    const int o = wave * 64 + lane;  // 0..255 output column

    float wr[64];
#pragma unroll
    for (int j = 0; j < 16; ++j) {
        const float4 t = *(const float4*)(W + o * 64 + j * 4);
        wr[4 * j + 0] = t.x; wr[4 * j + 1] = t.y;
        wr[4 * j + 2] = t.z; wr[4 * j + 3] = t.w;
    }
    const float bias = bb[o];
    const int n0 = blockIdx.x * 64;
    for (int ni = 0; ni < 64; ++ni) {
        const int nn = n0 + ni;
        const int nc = nn < n ? nn : n - 1;
        const float4* __restrict__ xr4 = (const float4*)(x + (size_t)nc * 64);

        float4 xv[4], xn[4];
#pragma unroll
        for (int u = 0; u < 4; ++u) xv[u] = xr4[u];

        float a0 = 0.f, a1 = 0.f, a2 = 0.f, a3 = 0.f;
#pragma unroll
        for (int c = 0; c < 4; ++c) {
            if (c < 3) {
#pragma unroll
                for (int u = 0; u < 4; ++u) xn[u] = xr4[4 * (c + 1) + u];
            }
#pragma unroll
            for (int u = 0; u < 4; ++u) {
                const int j = 4 * c + u;
                a0 = fmaf(wr[4 * j + 0], xv[u].x, a0);
                a1 = fmaf(wr[4 * j + 1], xv[u].y, a1);
                a2 = fmaf(wr[4 * j + 2], xv[u].z, a2);
                a3 = fmaf(wr[4 * j + 3], xv[u].w, a3);
            }
            if (c < 3) {
#pragma unroll
                for (int u = 0; u < 4; ++u) xv[u] = xn[u];
            }
        }
        const float val = (a0 + a1) + (a2 + a3) + bias;
        if (nn < n) {
            const size_t oi = (size_t)nn * DMODEL + o;
            if (blockIdx.y == 0)      qO[oi] = val;
            else if (blockIdx.y == 1) ((unsigned short*)kvO)[oi * 2 + 0] = f2bf(val);
            else if (blockIdx.y == 2) ((unsigned short*)kvO)[oi * 2 + 1] = f2bf(val);
            else                      sO[oi] = val;
        }
    }
}

// ---------------------------------------------------------------------------
// Per-dst-node attention: one wave per node, online softmax over CSR edges.
// kv is channel-interleaved bf16 (k lo16, v hi16): a node's kv row is 1KB
// contiguous; each lane reads ONE uint4 (16B, channels c0..c0+3) -> the whole
// edge gather is a single fully-coalesced 1KB dwordx4 wave transaction.
// 1-deep software pipeline: next edge's kv row in flight during the update.
// NOTE: ob aliases qb (fp32) — each wave reads only its own node's q row,
// before the single terminal write to that row; no other wave touches it.
__global__ __launch_bounds__(256) void attn_kernel(
        const float* __restrict__ qb, const unsigned int* __restrict__ kvb,
        const int* __restrict__ offs, const int* __restrict__ ssrc,
        float* __restrict__ ob, int n) {
    const int wave = threadIdx.x >> 6, lane = threadIdx.x & 63;
    const int node = blockIdx.x * 4 + wave;
    if (node >= n) return;
    const int c0 = lane * 4;

    const float4 q4 = *(const float4*)(qb + (size_t)node * DMODEL + c0);
    const int start = offs[node];
    const int end = offs[node + 1];

    float m = -INFINITY, ssum = 0.f;
    float4 acc = {0.f, 0.f, 0.f, 0.f};

    uint4 kvc = {0u, 0u, 0u, 0u};
    int sn_nxt = 0;
    if (start < end) {
        const int sn0 = ssrc[start];
        kvc = *(const uint4*)(kvb + (size_t)sn0 * DMODEL + c0);
        if (start + 1 < end) sn_nxt = ssrc[start + 1];
    }

    for (int i = start; i < end; ++i) {
        uint4 kvn = {0u, 0u, 0u, 0u};
        if (i + 1 < end) {  // wave-uniform
            kvn = *(const uint4*)(kvb + (size_t)sn_nxt * DMODEL + c0);
        }
        const int sn2 = (i + 2 < end) ? ssrc[i + 2] : 0;

        float p = q4.x * bf2f((unsigned short)(kvc.x & 0xFFFFu))
                + q4.y * bf2f((unsigned short)(kvc.y & 0xFFFFu))
                + q4.z * bf2f((unsigned short)(kvc.z & 0xFFFFu))
                + q4.w * bf2f((unsigned short)(kvc.w & 0xFFFFu));
        // reduce within 16-lane head group
        p += __shfl_xor(p, 1);
        p += __shfl_xor(p, 2);
        p += __shfl_xor(p, 4);
        p += __shfl_xor(p, 8);
        const float a = p * 0.125f;  // / sqrt(64)

        const float mnew = fmaxf(m, a);
        const float r = __expf(m - mnew);    // exp(-inf)=0 on first edge
        const float pe = __expf(a - mnew);
        ssum = ssum * r + pe;
        acc.x = acc.x * r + bf2f((unsigned short)(kvc.x >> 16)) * pe;
        acc.y = acc.y * r + bf2f((unsigned short)(kvc.y >> 16)) * pe;
        acc.z = acc.z * r + bf2f((unsigned short)(kvc.z >> 16)) * pe;
        acc.w = acc.w * r + bf2f((unsigned short)(kvc.w >> 16)) * pe;
        m = mnew;

        kvc = kvn; sn_nxt = sn2;
    }
    const float inv = (end > start) ? 1.f / ssum : 0.f;
    float4 o;
    o.x = acc.x * inv; o.y = acc.y * inv; o.z = acc.z * inv; o.w = acc.w * inv;
    *(float4*)(ob + (size_t)node * DMODEL + c0) = o;
}

// ---------------------------------------------------------------------------
// beta-gate + LayerNorm + proj(256->64) + residual + relu.
// One wave processes NPW=8 nodes. Phase A: beta-gate + LN per node, all 8 LN
// rows kept in registers (ln4[8]; lane l holds channels 4l..4l+3).
// Phase B: proj WITHOUT LDS — weights read directly from global (W[lane][4j..]
// one float4/lane/j, 64KB/wave from the L2-resident 64KB Wproj; reused across
// all 8 nodes), and the ln broadcast uses v_readlane (VALU) instead of
// __shfl/ds_bpermute. (Round-7: old LDS version was LDS-pipe/latency-bound at
// 19% occupancy; this zero-LDS form dropped post out of the top-5 in round 10.)
__global__ __launch_bounds__(256) void post_kernel(
        const float* __restrict__ attn, const float* __restrict__ skip,
        const float* __restrict__ x,
        const float* __restrict__ Wbeta,
        const float* __restrict__ ln_g, const float* __restrict__ ln_b,
        const float* __restrict__ Wproj, const float* __restrict__ bproj,
        float* __restrict__ out, int n) {
    const int wave = threadIdx.x >> 6, lane = threadIdx.x & 63;
    const int c0 = lane * 4;
    const float4 wb0 = *(const float4*)(Wbeta + c0);
    const float4 wb1 = *(const float4*)(Wbeta + 256 + c0);
    const float4 wb2 = *(const float4*)(Wbeta + 512 + c0);
    const float4 g4 = *(const float4*)(ln_g + c0);
    const float4 bb4 = *(const float4*)(ln_b + c0);
    const float bp = bproj[lane];

    const int base = (blockIdx.x * 4 + wave) * NPW;
    float4 ln4[NPW];

    // ---- phase A: beta-gate + LayerNorm per node (results in registers)
#pragma unroll
    for (int ni = 0; ni < NPW; ++ni) {
        const int nn = base + ni;
        const int nc = (nn < n) ? nn : n - 1;  // clamp; tail discarded at store
        const float4 o4 = *(const float4*)(attn + (size_t)nc * DMODEL + c0);
        const float4 s4 = *(const float4*)(skip + (size_t)nc * DMODEL + c0);

        float bpart = o4.x * (wb0.x + wb2.x) + s4.x * (wb1.x - wb2.x)
                    + o4.y * (wb0.y + wb2.y) + s4.y * (wb1.y - wb2.y)
                    + o4.z * (wb0.z + wb2.z) + s4.z * (wb1.z - wb2.z)
                    + o4.w * (wb0.w + wb2.w) + s4.w * (wb1.w - wb2.w);
#pragma unroll
        for (int mk = 1; mk <= 32; mk <<= 1) bpart += __shfl_xor(bpart, mk);
        const float beta = 1.f / (1.f + __expf(-bpart));

        float4 u;
        u.x = beta * s4.x + (1.f - beta) * o4.x;
        u.y = beta * s4.y + (1.f - beta) * o4.y;
        u.z = beta * s4.z + (1.f - beta) * o4.z;
        u.w = beta * s4.w + (1.f - beta) * o4.w;

        float ps = u.x + u.y + u.z + u.w;
        float pq = u.x * u.x + u.y * u.y + u.z * u.z + u.w * u.w;
#pragma unroll
        for (int mk = 1; mk <= 32; mk <<= 1) {
            ps += __shfl_xor(ps, mk);
            pq += __shfl_xor(pq, mk);
        }
        const float mu = ps * (1.f / 256.f);
        const float var = pq * (1.f / 256.f) - mu * mu;
        const float rstd = rsqrtf(var + 1e-5f);

        ln4[ni].x = (u.x - mu) * rstd * g4.x + bb4.x;
        ln4[ni].y = (u.y - mu) * rstd * g4.y + bb4.y;
        ln4[ni].z = (u.z - mu) * rstd * g4.z + bb4.z;
        ln4[ni].w = (u.w - mu) * rstd * g4.w + bb4.w;
    }

    // ---- phase B: proj for all 8 nodes; weight float4 read once per j
    // (global, L2-resident), ln broadcast via v_readlane (uniform unrolled j)
    float acc[NPW];
#pragma unroll
    for (int ni = 0; ni < NPW; ++ni) acc[ni] = bp;

    const float4* __restrict__ Wp4 = (const float4*)Wproj;  // [64 rows][64 chunks]
#pragma unroll 4
    for (int j = 0; j < 64; ++j) {
        const float4 w = Wp4[lane * 64 + j];  // W[lane][4j..4j+3]
#pragma unroll
        for (int ni = 0; ni < NPW; ++ni) {
            acc[ni] = fmaf(w.x, rdl(ln4[ni].x, j), acc[ni]);
            acc[ni] = fmaf(w.y, rdl(ln4[ni].y, j), acc[ni]);
            acc[ni] = fmaf(w.z, rdl(ln4[ni].z, j), acc[ni]);
            acc[ni] = fmaf(w.w, rdl(ln4[ni].w, j), acc[ni]);
        }
    }

#pragma unroll
    for (int ni = 0; ni < NPW; ++ni) {
        const int nn = base + ni;
        if (nn < n) {
            const float res = acc[ni] + x[(size_t)nn * HID + lane];
            out[(size_t)nn * HID + lane] = fmaxf(res, 0.f);
        }
    }
}

// ---------------------------------------------------------------------------
extern "C" void kernel_launch(void* const* d_in, const int* in_sizes, int n_in,
                              void* d_out, int out_size, void* d_ws, size_t ws_size,
                              hipStream_t stream) {
    const float* x     = (const float*)d_in[0];
    const void*  ei    = d_in[1];
    const float* Wq    = (const float*)d_in[2];
    const float* bq    = (const float*)d_in[3];
    const float* Wk    = (const float*)d_in[4];
    const float* bk    = (const float*)d_in[5];
    const float* Wv    = (const float*)d_in[6];
    const float* bv    = (const float*)d_in[7];
    const float* Ws    = (const float*)d_in[8];
    const float* bs    = (const float*)d_in[9];
    const float* Wbeta = (const float*)d_in[10];
    const float* lng   = (const float*)d_in[11];
    const float* lnb   = (const float*)d_in[12];
    const float* Wp    = (const float*)d_in[13];
    const float* bp    = (const float*)d_in[14];
    float* out = (float*)d_out;

    const int N = in_sizes[0] / HID;
    const int E = in_sizes[1] / 2;
    const int NB = (N + 1023) / 1024;

    char* w = (char*)d_ws;
    size_t off = 0;
    auto take = [&](size_t bytes) -> char* {
        char* p = w + off;
        off += (bytes + 255) & ~(size_t)255;
        return p;
    };
    float*        qb     = (float*)take((size_t)N * DMODEL * 4);
    unsigned int* kvb    = (unsigned int*)take((size_t)N * DMODEL * 4);
    float*        sb     = (float*)take((size_t)N * DMODEL * 4);
    int*          deg    = (int*)take((size_t)N * 4);
    int*          loc    = (int*)take((size_t)N * 4);
    int*          bsum   = (int*)take((size_t)NB * 4);
    int*          offs   = (int*)take((size_t)(N + 1) * 4);
    int*          cursor = (int*)take((size_t)N * 4);
    int*          ssrc   = (int*)take((size_t)E * 4);
    int*          flag   = (int*)take(256);
    float*        ob     = qb;  // safe alias: see attn_kernel note

    detect_i64_kernel<<<1, 64, 0, stream>>>((const int*)ei, flag);
    hipMemsetAsync(deg, 0, (size_t)N * 4, stream);
    hist_kernel<<<(E + 255) / 256, 256, 0, stream>>>(ei, flag, deg, E);
    scanA_kernel<<<NB, 1024, 0, stream>>>(deg, loc, bsum, N);
    scanB_kernel<<<1, 1024, 0, stream>>>(bsum, NB);
    scanC_kernel<<<(N + 256) / 256, 256, 0, stream>>>(deg, loc, bsum, offs, cursor, N, NB);
    fill_kernel<<<(E + 255) / 256, 256, 0, stream>>>(ei, flag, cursor, ssrc, E);
    qkvs_gemm_kernel<<<dim3((N + 63) / 64, 4), 256, 0, stream>>>(
        x, Wq, bq, Wk, bk, Wv, bv, Ws, bs, qb, kvb, sb, N);
    attn_kernel<<<(N + 3) / 4, 256, 0, stream>>>(qb, kvb, offs, ssrc, ob, N);
    post_kernel<<<(N + 4 * NPW - 1) / (4 * NPW), 256, 0, stream>>>(
        ob, sb, x, Wbeta, lng, lnb, Wp, bp, out, N);
}